// Round 2
// baseline (830.945 us; speedup 1.0000x reference)
//
#include <hip/hip_runtime.h>
#include <math.h>

#define NB 16
#define VN 49
#define VD 2048
#define AN 64
#define AE 128
#define AH 64
#define EPS 1e-5f
#define SCALE_V 0.022097086912079608f  // 1/sqrt(2048)
#define SCALE_A 0.08838834764831845f   // 1/sqrt(128)

// ---------- vision transpose: v[b][n][d] = Vis[b][d][n] ----------
__global__ void k_transpose(const float* __restrict__ Vis, float* __restrict__ v) {
    __shared__ float t[32][33];
    int b = blockIdx.z;
    int d0 = blockIdx.x * 32;
    int n0 = blockIdx.y * 32;
    int tx = threadIdx.x, ty = threadIdx.y; // 32 x 8
    for (int k = 0; k < 4; k++) {
        int d = d0 + ty + 8 * k;
        int n = n0 + tx;
        float val = 0.f;
        if (n < VN) val = Vis[(size_t)b * VD * VN + (size_t)d * VN + n];
        t[ty + 8 * k][tx] = val;
    }
    __syncthreads();
    for (int k = 0; k < 4; k++) {
        int n = n0 + ty + 8 * k;
        int d = d0 + tx;
        if (n < VN) v[(size_t)b * VN * VD + (size_t)n * VD + d] = t[tx][ty + 8 * k];
    }
}

// ---------- audio hidden pre-BN: xa[b][n][h] = ab1[h] + sum_d a[b][n][d]*aW1[h][d] ----------
__global__ void k_xa(const float* __restrict__ a, const float* __restrict__ aW1,
                     const float* __restrict__ ab1, float* __restrict__ xa) {
    int idx = blockIdx.x * blockDim.x + threadIdx.x; // NB*AN*AH = 65536
    int h = idx & (AH - 1);
    int bn = idx >> 6;
    const float* ar = a + (size_t)bn * AE;
    const float* wr = aW1 + (size_t)h * AE;
    float s = ab1[h];
    for (int d = 0; d < AE; d += 4) {
        float4 w = *(const float4*)(wr + d);
        float4 av = *(const float4*)(ar + d);
        s += av.x * w.x + av.y * w.y + av.z * w.z + av.w * w.w;
    }
    xa[idx] = s;
}

// ---------- generic BN stats: per channel c (dim1 of (B,C,L)), biased var ----------
__global__ void k_bnstats(const float* __restrict__ x, int C, int L,
                          const float* __restrict__ g, const float* __restrict__ beta,
                          float* __restrict__ scale, float* __restrict__ shift) {
    int c = blockIdx.x;
    int N = NB * L;
    double s = 0.0, s2 = 0.0;
    for (int i = threadIdx.x; i < N; i += blockDim.x) {
        int b = i / L, l = i - b * L;
        float val = x[((size_t)b * C + c) * L + l];
        s += val; s2 += (double)val * val;
    }
    __shared__ double sh[256], sh2[256];
    sh[threadIdx.x] = s; sh2[threadIdx.x] = s2;
    __syncthreads();
    for (int o = 128; o > 0; o >>= 1) {
        if (threadIdx.x < o) { sh[threadIdx.x] += sh[threadIdx.x + o]; sh2[threadIdx.x] += sh2[threadIdx.x + o]; }
        __syncthreads();
    }
    if (threadIdx.x == 0) {
        double mean = sh[0] / N;
        double var = sh2[0] / N - mean * mean;
        float sc = g[c] * rsqrtf((float)var + EPS);
        scale[c] = sc;
        shift[c] = beta[c] - (float)mean * sc;
    }
}

// ---------- elementwise BN apply + relu, in place ----------
__global__ void k_bnapply(float* __restrict__ x, int C, int L,
                          const float* __restrict__ scale, const float* __restrict__ shift,
                          int total) {
    int idx = blockIdx.x * blockDim.x + threadIdx.x;
    if (idx >= total) return;
    int c = (idx / L) % C;
    x[idx] = fmaxf(x[idx] * scale[c] + shift[c], 0.f);
}

// ---------- aquery[b][n][d] = ab2[d] + sum_h relu(bn(xa))[b][n][h]*aW2[d][h] ----------
__global__ void k_aquery(const float* __restrict__ xa, const float* __restrict__ aW2,
                         const float* __restrict__ ab2, const float* __restrict__ sc,
                         const float* __restrict__ sh, float* __restrict__ aq) {
    __shared__ float ah[AH];
    int bn = blockIdx.x;   // b*AN + n
    int n = bn & (AN - 1);
    int t = threadIdx.x;   // 128
    if (t < AH) ah[t] = fmaxf(xa[(size_t)bn * AH + t] * sc[n] + sh[n], 0.f);
    __syncthreads();
    float s = ab2[t];
    const float* wr = aW2 + (size_t)t * AH;
    for (int h = 0; h < AH; h++) s += ah[h] * wr[h];
    aq[(size_t)bn * AE + t] = s;
}

// ---------- akeys pre-BN: ak[b][o][d] = kab[o] + sum_n kaW[o][n]*a[b][n][d] ----------
__global__ void k_akeys(const float* __restrict__ a, const float* __restrict__ kaW,
                        const float* __restrict__ kab, float* __restrict__ ak) {
    int idx = blockIdx.x * blockDim.x + threadIdx.x; // NB*AN*AE = 131072
    int d = idx & (AE - 1);
    int bo = idx >> 7;
    int o = bo & (AN - 1);
    int b = bo >> 6;
    float s = kab[o];
    const float* ap = a + (size_t)b * AN * AE + d;
    const float* wr = kaW + (size_t)o * AN;
    for (int n = 0; n < AN; n++) s += wr[n] * ap[(size_t)n * AE];
    ak[idx] = s;
}

// ---------- vision hidden pre-BN: vh[b][n][h] = vb1[h] + sum_d v[b][n][d]*vW1[h][d] ----------
__global__ void k_vh(const float* __restrict__ v, const float* __restrict__ vW1,
                     const float* __restrict__ vb1, float* __restrict__ vh) {
    __shared__ float vl[VD];
    int bn = blockIdx.x;  // b*VN + n
    int t = threadIdx.x;  // 64
    const float* vr = v + (size_t)bn * VD;
    for (int d = t; d < VD; d += 64) vl[d] = vr[d];
    __syncthreads();
    if (t < VN) {
        const float* wr = vW1 + (size_t)t * VD;
        float s = vb1[t];
        for (int d = 0; d < VD; d += 4) {
            float4 w = *(const float4*)(wr + d);
            s += vl[d] * w.x + vl[d + 1] * w.y + vl[d + 2] * w.z + vl[d + 3] * w.w;
        }
        vh[(size_t)bn * VN + t] = s;
    }
}

// ---------- vquery[b][n][d] = vb2[d] + sum_h vh_act[b][n][h]*vW2[d][h] ----------
__global__ void k_vquery(const float* __restrict__ vh, const float* __restrict__ vW2,
                         const float* __restrict__ vb2, float* __restrict__ vq) {
    __shared__ float hl[VN];
    int bn = blockIdx.x;
    int t = threadIdx.x; // 256
    if (t < VN) hl[t] = vh[(size_t)bn * VN + t];
    __syncthreads();
    for (int d = t; d < VD; d += 256) {
        const float* wr = vW2 + (size_t)d * VN;
        float s = vb2[d];
        for (int h = 0; h < VN; h++) s += hl[h] * wr[h];
        vq[(size_t)bn * VD + d] = s;
    }
}

// ---------- vkeys pre-BN: vk[b][o][d] = kvb[o] + sum_n kvW[o][n]*v[b][n][d] ----------
__global__ void k_vkeys(const float* __restrict__ v, const float* __restrict__ kvW,
                        const float* __restrict__ kvb, float* __restrict__ vk) {
    int idx = blockIdx.x * blockDim.x + threadIdx.x; // 16*49*2048
    int d = idx & (VD - 1);
    int bo = idx >> 11;
    int o = bo % VN;
    int b = bo / VN;
    float s = kvb[o];
    const float* vp = v + (size_t)b * VN * VD + d;
    const float* wr = kvW + (size_t)o * VN;
    for (int n = 0; n < VN; n++) s += wr[n] * vp[(size_t)n * VD];
    vk[idx] = s;
}

// ---------- pass1: per-row (d) online softmax stats of S = scale * relu(bn(K))^T Q ----------
// BN+ReLU applied to K at staging (channel = K row index).
__global__ __launch_bounds__(256) void k_pass1(const float* __restrict__ K, const float* __restrict__ Q,
                                               const float* __restrict__ sc, const float* __restrict__ shf,
                                               float* __restrict__ mrow, float* __restrict__ invl) {
    __shared__ __align__(16) float Kl[VN][64];
    __shared__ __align__(16) float Ql[VN][128];
    int b = blockIdx.y;
    int d0 = blockIdx.x * 64;
    int tid = threadIdx.x;
    int ti = tid >> 4, tj = tid & 15;
    const float* Kb = K + (size_t)b * VN * VD;
    const float* Qb = Q + (size_t)b * VN * VD;
    for (int idx = tid; idx < VN * 16; idx += 256) {
        int r = idx >> 4, c = (idx & 15) << 2;
        float4 x = *(const float4*)(Kb + (size_t)r * VD + d0 + c);
        float s = sc[r], h = shf[r];
        float4 y;
        y.x = fmaxf(x.x * s + h, 0.f); y.y = fmaxf(x.y * s + h, 0.f);
        y.z = fmaxf(x.z * s + h, 0.f); y.w = fmaxf(x.w * s + h, 0.f);
        *(float4*)&Kl[r][c] = y;
    }
    float m[4] = {-INFINITY, -INFINITY, -INFINITY, -INFINITY};
    float l[4] = {0.f, 0.f, 0.f, 0.f};
    for (int e0 = 0; e0 < VD; e0 += 128) {
        __syncthreads();
        for (int idx = tid; idx < VN * 32; idx += 256) {
            int r = idx >> 5, c = (idx & 31) << 2;
            *(float4*)&Ql[r][c] = *(const float4*)(Qb + (size_t)r * VD + e0 + c);
        }
        __syncthreads();
        float acc[4][8];
        #pragma unroll
        for (int i = 0; i < 4; i++)
            #pragma unroll
            for (int j = 0; j < 8; j++) acc[i][j] = 0.f;
        for (int n = 0; n < VN; n++) {
            float4 k4 = *(const float4*)&Kl[n][ti << 2];
            float4 qa = *(const float4*)&Ql[n][tj << 2];
            float4 qb = *(const float4*)&Ql[n][64 + (tj << 2)];
            float kk[4] = {k4.x, k4.y, k4.z, k4.w};
            float qq[8] = {qa.x, qa.y, qa.z, qa.w, qb.x, qb.y, qb.z, qb.w};
            #pragma unroll
            for (int i = 0; i < 4; i++)
                #pragma unroll
                for (int j = 0; j < 8; j++) acc[i][j] += kk[i] * qq[j];
        }
        #pragma unroll
        for (int i = 0; i < 4; i++) {
            float tm = -INFINITY;
            #pragma unroll
            for (int j = 0; j < 8; j++) { acc[i][j] *= SCALE_V; tm = fmaxf(tm, acc[i][j]); }
            for (int o = 1; o < 16; o <<= 1) tm = fmaxf(tm, __shfl_xor(tm, o, 64));
            float mn = fmaxf(m[i], tm);
            float f = __expf(m[i] - mn);
            float se = 0.f;
            #pragma unroll
            for (int j = 0; j < 8; j++) se += __expf(acc[i][j] - mn);
            l[i] = l[i] * f + se;
            m[i] = mn;
        }
    }
    #pragma unroll
    for (int i = 0; i < 4; i++) {
        float li = l[i];
        for (int o = 1; o < 16; o <<= 1) li += __shfl_xor(li, o, 64);
        if (tj == 0) {
            int d = d0 + (ti << 2) + i;
            mrow[(size_t)b * VD + d] = m[i];
            invl[(size_t)b * VD + d] = 1.f / li;
        }
    }
}

// ---------- pass2: O[n,e] = sum_d (V[n,d]*invl[d]) * exp(scale*S[d,e]-m[d]) ----------
// e-tile = 64 -> LDS ~59 KB -> 2 blocks/CU; grid 512 -> 2 resident blocks/CU.
// BN+ReLU applied to K at staging.
__global__ __launch_bounds__(256) void k_pass2(const float* __restrict__ K, const float* __restrict__ Q,
                                               const float* __restrict__ V, const float* __restrict__ mrow,
                                               const float* __restrict__ invl, const float* __restrict__ sc,
                                               const float* __restrict__ shf, float* __restrict__ Out) {
    __shared__ __align__(16) float Ql[VN][64];   // 12.25 KB (e-tile)
    __shared__ __align__(16) float Kl[VN][64];   // 12.25 KB (d-tile)
    __shared__ __align__(16) float Vt[64][68];   // 17 KB   Vt[dl][n] = V[n][d0+dl]*invl
    __shared__ __align__(16) float Pl[64][68];   // 17 KB
    __shared__ float ml[64];
    int b = blockIdx.y;
    int e0 = blockIdx.x * 64;
    int tid = threadIdx.x;
    int ti = tid >> 4, tj = tid & 15;
    const float* Kb = K + (size_t)b * VN * VD;
    const float* Qb = Q + (size_t)b * VN * VD;
    const float* Vb = V + (size_t)b * VN * VD;
    for (int idx = tid; idx < VN * 16; idx += 256) {
        int r = idx >> 4, c = (idx & 15) << 2;
        *(float4*)&Ql[r][c] = *(const float4*)(Qb + (size_t)r * VD + e0 + c);
    }
    for (int idx = tid; idx < 64 * 68; idx += 256) ((float*)Vt)[idx] = 0.f;
    float oacc[4][4];
    #pragma unroll
    for (int i = 0; i < 4; i++)
        #pragma unroll
        for (int j = 0; j < 4; j++) oacc[i][j] = 0.f;

    for (int d0 = 0; d0 < VD; d0 += 64) {
        __syncthreads();  // protect Kl/Vt/ml/Pl from previous iteration readers (also covers Ql/Vt init)
        for (int idx = tid; idx < VN * 16; idx += 256) {
            int r = idx >> 4, c = (idx & 15) << 2;
            float4 x = *(const float4*)(Kb + (size_t)r * VD + d0 + c);
            float s = sc[r], h = shf[r];
            float4 y;
            y.x = fmaxf(x.x * s + h, 0.f); y.y = fmaxf(x.y * s + h, 0.f);
            y.z = fmaxf(x.z * s + h, 0.f); y.w = fmaxf(x.w * s + h, 0.f);
            *(float4*)&Kl[r][c] = y;
        }
        for (int idx = tid; idx < VN * 16; idx += 256) {
            int n = idx >> 4, c = (idx & 15) << 2;
            float4 v4 = *(const float4*)(Vb + (size_t)n * VD + d0 + c);
            float4 il4 = *(const float4*)(invl + (size_t)b * VD + d0 + c);
            Vt[c + 0][n] = v4.x * il4.x;
            Vt[c + 1][n] = v4.y * il4.y;
            Vt[c + 2][n] = v4.z * il4.z;
            Vt[c + 3][n] = v4.w * il4.w;
        }
        if (tid < 64) ml[tid] = mrow[(size_t)b * VD + d0 + tid];
        __syncthreads();
        // S tile: acc[i][j] = sum_n Kl[n][ti*4+i] * Ql[n][tj*4+j]
        float acc[4][4];
        #pragma unroll
        for (int i = 0; i < 4; i++)
            #pragma unroll
            for (int j = 0; j < 4; j++) acc[i][j] = 0.f;
        for (int n = 0; n < VN; n++) {
            float4 k4 = *(const float4*)&Kl[n][ti << 2];
            float4 q4 = *(const float4*)&Ql[n][tj << 2];
            float kk[4] = {k4.x, k4.y, k4.z, k4.w};
            float qq[4] = {q4.x, q4.y, q4.z, q4.w};
            #pragma unroll
            for (int i = 0; i < 4; i++)
                #pragma unroll
                for (int j = 0; j < 4; j++) acc[i][j] += kk[i] * qq[j];
        }
        int dbase = ti << 2;
        #pragma unroll
        for (int i = 0; i < 4; i++) {
            float mi = ml[dbase + i];
            float4 p4;
            p4.x = __expf(acc[i][0] * SCALE_V - mi);
            p4.y = __expf(acc[i][1] * SCALE_V - mi);
            p4.z = __expf(acc[i][2] * SCALE_V - mi);
            p4.w = __expf(acc[i][3] * SCALE_V - mi);
            *(float4*)&Pl[dbase + i][tj << 2] = p4;
        }
        __syncthreads();
        // O accumulate: oacc[i][j] += sum_dd Vt[dd][ti*4+i] * Pl[dd][tj*4+j]
        for (int dd = 0; dd < 64; dd++) {
            float4 v4 = *(const float4*)&Vt[dd][ti << 2];
            float4 p4 = *(const float4*)&Pl[dd][tj << 2];
            float vv[4] = {v4.x, v4.y, v4.z, v4.w};
            float pp[4] = {p4.x, p4.y, p4.z, p4.w};
            #pragma unroll
            for (int i = 0; i < 4; i++)
                #pragma unroll
                for (int j = 0; j < 4; j++) oacc[i][j] += vv[i] * pp[j];
        }
    }
    #pragma unroll
    for (int i = 0; i < 4; i++) {
        int n = (ti << 2) + i;
        if (n < VN) {
            float4 o4 = {oacc[i][0], oacc[i][1], oacc[i][2], oacc[i][3]};
            *(float4*)(Out + (size_t)b * VN * VD + (size_t)n * VD + e0 + (tj << 2)) = o4;
        }
    }
}

// ---------- audio scores: softmax_e( scale * sum_n K[n,d] Q[n,e] ) ----------
__global__ void k_scoresA(const float* __restrict__ Kk, const float* __restrict__ Qq,
                          float* __restrict__ S) {
    __shared__ __align__(16) float Kl[AN * AE];
    __shared__ __align__(16) float Ql[AN * AE];
    int b = blockIdx.x;
    int tid = threadIdx.x;
    int wave = tid >> 6, lane = tid & 63;
    const float* Kb = Kk + (size_t)b * AN * AE;
    const float* Qb = Qq + (size_t)b * AN * AE;
    for (int idx = tid; idx < AN * AE / 4; idx += 256) {
        *(float4*)&Kl[idx << 2] = *(const float4*)(Kb + (idx << 2));
        *(float4*)&Ql[idx << 2] = *(const float4*)(Qb + (idx << 2));
    }
    __syncthreads();
    for (int d2 = wave * 2; d2 < AE; d2 += 8) {   // 2 rows per wave per iter
        float s00 = 0, s01 = 0, s10 = 0, s11 = 0;
        for (int n = 0; n < AN; n++) {
            float k0 = Kl[n * AE + d2];
            float k1 = Kl[n * AE + d2 + 1];
            float q0 = Ql[n * AE + lane];
            float q1 = Ql[n * AE + 64 + lane];
            s00 += k0 * q0; s01 += k0 * q1;
            s10 += k1 * q0; s11 += k1 * q1;
        }
        s00 *= SCALE_A; s01 *= SCALE_A; s10 *= SCALE_A; s11 *= SCALE_A;
        // row d2
        float mx = fmaxf(s00, s01);
        for (int o = 1; o < 64; o <<= 1) mx = fmaxf(mx, __shfl_xor(mx, o, 64));
        float e0v = __expf(s00 - mx), e1v = __expf(s01 - mx);
        float sm = e0v + e1v;
        for (int o = 1; o < 64; o <<= 1) sm += __shfl_xor(sm, o, 64);
        float inv = 1.f / sm;
        S[(size_t)b * AE * AE + (size_t)d2 * AE + lane] = e0v * inv;
        S[(size_t)b * AE * AE + (size_t)d2 * AE + 64 + lane] = e1v * inv;
        // row d2+1
        mx = fmaxf(s10, s11);
        for (int o = 1; o < 64; o <<= 1) mx = fmaxf(mx, __shfl_xor(mx, o, 64));
        e0v = __expf(s10 - mx); e1v = __expf(s11 - mx);
        sm = e0v + e1v;
        for (int o = 1; o < 64; o <<= 1) sm += __shfl_xor(sm, o, 64);
        inv = 1.f / sm;
        S[(size_t)b * AE * AE + (size_t)(d2 + 1) * AE + lane] = e0v * inv;
        S[(size_t)b * AE * AE + (size_t)(d2 + 1) * AE + 64 + lane] = e1v * inv;
    }
}

// ---------- a_out[b][n][e] = sum_d a[b][n][d]*S[b][d][e] ----------
__global__ void k_aout(const float* __restrict__ a, const float* __restrict__ S,
                       float* __restrict__ out) {
    int b = blockIdx.x;
    const float* ap = a + (size_t)b * AN * AE;
    const float* Sb = S + (size_t)b * AE * AE;
    for (int idx = threadIdx.x; idx < AN * AE; idx += blockDim.x) {
        int n = idx >> 7, e = idx & 127;
        float s = 0.f;
        for (int d = 0; d < AE; d++) s += ap[n * AE + d] * Sb[d * AE + e];
        out[(size_t)b * AN * AE + idx] = s;
    }
}

extern "C" void kernel_launch(void* const* d_in, const int* in_sizes, int n_in,
                              void* d_out, int out_size, void* d_ws, size_t ws_size,
                              hipStream_t stream) {
    const float* Vis  = (const float*)d_in[0];
    const float* Aud  = (const float*)d_in[1];
    const float* aW1  = (const float*)d_in[2];
    const float* ab1  = (const float*)d_in[3];
    const float* a_g1 = (const float*)d_in[4];
    const float* a_b1 = (const float*)d_in[5];
    const float* aW2  = (const float*)d_in[6];
    const float* ab2  = (const float*)d_in[7];
    const float* vW1  = (const float*)d_in[8];
    const float* vb1  = (const float*)d_in[9];
    const float* v_g1 = (const float*)d_in[10];
    const float* v_b1 = (const float*)d_in[11];
    const float* vW2  = (const float*)d_in[12];
    const float* vb2  = (const float*)d_in[13];
    const float* kaW  = (const float*)d_in[14];
    const float* kab  = (const float*)d_in[15];
    const float* ka_g = (const float*)d_in[16];
    const float* ka_b = (const float*)d_in[17];
    const float* kvW  = (const float*)d_in[18];
    const float* kvb  = (const float*)d_in[19];
    const float* kv_g = (const float*)d_in[20];
    const float* kv_b = (const float*)d_in[21];

    float* ws = (float*)d_ws;
    float* v       = ws;                      // 1,605,632
    float* vquery  = ws + 1605632;            // 1,605,632
    float* vkeys   = ws + 2 * 1605632;        // 1,605,632 (pre-BN; BN fused into pass1/pass2)
    float* vhbuf   = ws + 3 * 1605632;        // 38,416
    float* xa      = vhbuf + 38416;           // 65,536
    float* aquery  = xa + 65536;              // 131,072
    float* akeys   = aquery + 131072;         // 131,072
    float* scoresA = akeys + 131072;          // 262,144
    float* mrow    = scoresA + 262144;        // 32,768
    float* invl    = mrow + 32768;            // 32,768
    float* stats   = invl + 32768;            // 512
    // total ~21 MB of workspace

    float* vout = (float*)d_out;              // (16,49,2048)
    float* aout = vout + 1605632;             // (16,64,128)

    // vision transpose
    k_transpose<<<dim3(64, 2, 16), dim3(32, 8), 0, stream>>>(Vis, v);

    // audio query MLP
    k_xa<<<256, 256, 0, stream>>>(Aud, aW1, ab1, xa);
    k_bnstats<<<64, 256, 0, stream>>>(xa, 64, 64, a_g1, a_b1, stats + 0, stats + 64);
    k_aquery<<<NB * AN, 128, 0, stream>>>(xa, aW2, ab2, stats + 0, stats + 64, aquery);

    // audio keys
    k_akeys<<<512, 256, 0, stream>>>(Aud, kaW, kab, akeys);
    k_bnstats<<<64, 256, 0, stream>>>(akeys, 64, 128, ka_g, ka_b, stats + 128, stats + 192);
    k_bnapply<<<512, 256, 0, stream>>>(akeys, 64, 128, stats + 128, stats + 192, 131072);

    // vision query MLP
    k_vh<<<NB * VN, 64, 0, stream>>>(v, vW1, vb1, vhbuf);
    k_bnstats<<<49, 256, 0, stream>>>(vhbuf, 49, 49, v_g1, v_b1, stats + 256, stats + 320);
    k_bnapply<<<(38416 + 255) / 256, 256, 0, stream>>>(vhbuf, 49, 49, stats + 256, stats + 320, 38416);
    k_vquery<<<NB * VN, 256, 0, stream>>>(vhbuf, vW2, vb2, vquery);

    // vision keys: pre-BN GEMM + stats only; BN+ReLU fused into pass1/pass2 staging
    k_vkeys<<<6272, 256, 0, stream>>>(v, kvW, kvb, vkeys);
    k_bnstats<<<49, 256, 0, stream>>>(vkeys, 49, 2048, kv_g, kv_b, stats + 384, stats + 448);

    // vision attention (two-pass, no S materialization)
    k_pass1<<<dim3(32, 16), 256, 0, stream>>>(vkeys, vquery, stats + 384, stats + 448, mrow, invl);
    k_pass2<<<dim3(32, 16), 256, 0, stream>>>(vkeys, vquery, v, mrow, invl, stats + 384, stats + 448, vout);

    // audio attention
    k_scoresA<<<16, 256, 0, stream>>>(akeys, aquery, scoresA);
    k_aout<<<16, 256, 0, stream>>>(Aud, scoresA, aout);
}

// Round 3
// 634.021 us; speedup vs baseline: 1.3106x; 1.3106x over previous
//
#include <hip/hip_runtime.h>
#include <math.h>

#define NB 16
#define VN 49
#define VD 2048
#define AN 64
#define AE 128
#define AH 64
#define EPS 1e-5f
#define SCALE_V 0.022097086912079608f  // 1/sqrt(2048)
#define SCALE_A 0.08838834764831845f   // 1/sqrt(128)

typedef __attribute__((ext_vector_type(8))) short short8;
typedef __attribute__((ext_vector_type(8))) __bf16 bf16x8;
typedef __attribute__((ext_vector_type(4))) float f32x4;

__device__ __forceinline__ f32x4 mfma16(short8 a, short8 b, f32x4 c) {
    return __builtin_amdgcn_mfma_f32_16x16x32_bf16(
        __builtin_bit_cast(bf16x8, a), __builtin_bit_cast(bf16x8, b), c, 0, 0, 0);
}

__device__ __forceinline__ unsigned short f2bf(float x) {
    unsigned int u = __builtin_bit_cast(unsigned int, x);
    unsigned int r = (u + 0x7fffu + ((u >> 16) & 1u)) >> 16;  // RNE
    return (unsigned short)r;
}

// ---------- vision transpose: v[b][n][d] = Vis[b][d][n] ----------
__global__ void k_transpose(const float* __restrict__ Vis, float* __restrict__ v) {
    __shared__ float t[32][33];
    int b = blockIdx.z;
    int d0 = blockIdx.x * 32;
    int n0 = blockIdx.y * 32;
    int tx = threadIdx.x, ty = threadIdx.y; // 32 x 8
    for (int k = 0; k < 4; k++) {
        int d = d0 + ty + 8 * k;
        int n = n0 + tx;
        float val = 0.f;
        if (n < VN) val = Vis[(size_t)b * VD * VN + (size_t)d * VN + n];
        t[ty + 8 * k][tx] = val;
    }
    __syncthreads();
    for (int k = 0; k < 4; k++) {
        int n = n0 + ty + 8 * k;
        int d = d0 + tx;
        if (n < VN) v[(size_t)b * VN * VD + (size_t)n * VD + d] = t[tx][ty + 8 * k];
    }
}

// ---------- audio hidden pre-BN ----------
__global__ void k_xa(const float* __restrict__ a, const float* __restrict__ aW1,
                     const float* __restrict__ ab1, float* __restrict__ xa) {
    int idx = blockIdx.x * blockDim.x + threadIdx.x; // 65536
    int h = idx & (AH - 1);
    int bn = idx >> 6;
    const float* ar = a + (size_t)bn * AE;
    const float* wr = aW1 + (size_t)h * AE;
    float s = ab1[h];
    for (int d = 0; d < AE; d += 4) {
        float4 w = *(const float4*)(wr + d);
        float4 av = *(const float4*)(ar + d);
        s += av.x * w.x + av.y * w.y + av.z * w.z + av.w * w.w;
    }
    xa[idx] = s;
}

// ---------- BN stats ----------
__global__ void k_bnstats(const float* __restrict__ x, int C, int L,
                          const float* __restrict__ g, const float* __restrict__ beta,
                          float* __restrict__ scale, float* __restrict__ shift) {
    int c = blockIdx.x;
    int N = NB * L;
    double s = 0.0, s2 = 0.0;
    for (int i = threadIdx.x; i < N; i += blockDim.x) {
        int b = i / L, l = i - b * L;
        float val = x[((size_t)b * C + c) * L + l];
        s += val; s2 += (double)val * val;
    }
    __shared__ double sh[256], sh2[256];
    sh[threadIdx.x] = s; sh2[threadIdx.x] = s2;
    __syncthreads();
    for (int o = 128; o > 0; o >>= 1) {
        if (threadIdx.x < o) { sh[threadIdx.x] += sh[threadIdx.x + o]; sh2[threadIdx.x] += sh2[threadIdx.x + o]; }
        __syncthreads();
    }
    if (threadIdx.x == 0) {
        double mean = sh[0] / N;
        double var = sh2[0] / N - mean * mean;
        float sc = g[c] * rsqrtf((float)var + EPS);
        scale[c] = sc;
        shift[c] = beta[c] - (float)mean * sc;
    }
}

// ---------- BN apply + relu ----------
__global__ void k_bnapply(float* __restrict__ x, int C, int L,
                          const float* __restrict__ scale, const float* __restrict__ shift,
                          int total) {
    int idx = blockIdx.x * blockDim.x + threadIdx.x;
    if (idx >= total) return;
    int c = (idx / L) % C;
    x[idx] = fmaxf(x[idx] * scale[c] + shift[c], 0.f);
}

// ---------- aquery ----------
__global__ void k_aquery(const float* __restrict__ xa, const float* __restrict__ aW2,
                         const float* __restrict__ ab2, const float* __restrict__ sc,
                         const float* __restrict__ sh, float* __restrict__ aq) {
    __shared__ float ah[AH];
    int bn = blockIdx.x;
    int n = bn & (AN - 1);
    int t = threadIdx.x;   // 128
    if (t < AH) ah[t] = fmaxf(xa[(size_t)bn * AH + t] * sc[n] + sh[n], 0.f);
    __syncthreads();
    float s = ab2[t];
    const float* wr = aW2 + (size_t)t * AH;
    for (int h = 0; h < AH; h++) s += ah[h] * wr[h];
    aq[(size_t)bn * AE + t] = s;
}

// ---------- akeys pre-BN ----------
__global__ void k_akeys(const float* __restrict__ a, const float* __restrict__ kaW,
                        const float* __restrict__ kab, float* __restrict__ ak) {
    int idx = blockIdx.x * blockDim.x + threadIdx.x;
    int d = idx & (AE - 1);
    int bo = idx >> 7;
    int o = bo & (AN - 1);
    int b = bo >> 6;
    float s = kab[o];
    const float* ap = a + (size_t)b * AN * AE + d;
    const float* wr = kaW + (size_t)o * AN;
    for (int n = 0; n < AN; n++) s += wr[n] * ap[(size_t)n * AE];
    ak[idx] = s;
}

// ---------- vision hidden pre-BN ----------
__global__ void k_vh(const float* __restrict__ v, const float* __restrict__ vW1,
                     const float* __restrict__ vb1, float* __restrict__ vh) {
    __shared__ float vl[VD];
    int bn = blockIdx.x;
    int t = threadIdx.x;  // 64
    const float* vr = v + (size_t)bn * VD;
    for (int d = t; d < VD; d += 64) vl[d] = vr[d];
    __syncthreads();
    if (t < VN) {
        const float* wr = vW1 + (size_t)t * VD;
        float s = vb1[t];
        for (int d = 0; d < VD; d += 4) {
            float4 w = *(const float4*)(wr + d);
            s += vl[d] * w.x + vl[d + 1] * w.y + vl[d + 2] * w.z + vl[d + 3] * w.w;
        }
        vh[(size_t)bn * VN + t] = s;
    }
}

// ---------- vquery ----------
__global__ void k_vquery(const float* __restrict__ vh, const float* __restrict__ vW2,
                         const float* __restrict__ vb2, float* __restrict__ vq) {
    __shared__ float hl[VN];
    int bn = blockIdx.x;
    int t = threadIdx.x; // 256
    if (t < VN) hl[t] = vh[(size_t)bn * VN + t];
    __syncthreads();
    for (int d = t; d < VD; d += 256) {
        const float* wr = vW2 + (size_t)d * VN;
        float s = vb2[d];
        for (int h = 0; h < VN; h++) s += hl[h] * wr[h];
        vq[(size_t)bn * VD + d] = s;
    }
}

// ---------- vkeys pre-BN ----------
__global__ void k_vkeys(const float* __restrict__ v, const float* __restrict__ kvW,
                        const float* __restrict__ kvb, float* __restrict__ vk) {
    int idx = blockIdx.x * blockDim.x + threadIdx.x;
    int d = idx & (VD - 1);
    int bo = idx >> 11;
    int o = bo % VN;
    int b = bo / VN;
    float s = kvb[o];
    const float* vp = v + (size_t)b * VN * VD + d;
    const float* wr = kvW + (size_t)o * VN;
    for (int n = 0; n < VN; n++) s += wr[n] * vp[(size_t)n * VD];
    vk[idx] = s;
}

// ---------- prepQ: vquery[b][k][e] -> Qbf[b][e][k64] bf16, k padded 49->64 w/ 0 ----------
__global__ void k_prepQ(const float* __restrict__ vq, unsigned short* __restrict__ Qbf) {
    __shared__ unsigned short T[64 * 72];
    int dt = blockIdx.x, b = blockIdx.y;
    int tid = threadIdx.x; // 256
    for (int s = 0; s < 16; s++) {
        int idx = tid + 256 * s;
        int dl = idx & 63, n = idx >> 6;  // n 0..63
        float val = (n < VN) ? vq[((size_t)(b * VN + n)) * VD + dt * 64 + dl] : 0.f;
        T[dl * 72 + n] = f2bf(val);
    }
    __syncthreads();
    for (int s = 0; s < 2; s++) {
        int idx = tid + 256 * s;
        int r = idx >> 3, c = idx & 7;
        short8 vv = *(const short8*)&T[r * 72 + c * 8];
        *(short8*)(Qbf + ((size_t)(b * VD + dt * 64 + r)) * 64 + c * 8) = vv;
    }
}

// ---------- prepK: vkeys + BN + relu -> Kbf[b][d][k64] bf16 ----------
__global__ void k_prepK(const float* __restrict__ vk, const float* __restrict__ sc,
                        const float* __restrict__ sh, unsigned short* __restrict__ Kbf) {
    __shared__ unsigned short T[64 * 72];
    int dt = blockIdx.x, b = blockIdx.y;
    int tid = threadIdx.x;
    for (int s = 0; s < 16; s++) {
        int idx = tid + 256 * s;
        int dl = idx & 63, n = idx >> 6;
        float val = 0.f;
        if (n < VN) {
            float x = vk[((size_t)(b * VN + n)) * VD + dt * 64 + dl];
            val = fmaxf(x * sc[n] + sh[n], 0.f);
        }
        T[dl * 72 + n] = f2bf(val);
    }
    __syncthreads();
    for (int s = 0; s < 2; s++) {
        int idx = tid + 256 * s;
        int r = idx >> 3, c = idx & 7;
        short8 vv = *(const short8*)&T[r * 72 + c * 8];
        *(short8*)(Kbf + ((size_t)(b * VD + dt * 64 + r)) * 64 + c * 8) = vv;
    }
}

// ---------- pass1: invl[b][d] = 1/sum_e exp(SCALE_V * S[d][e]) (no max-subtract; |arg| small) ----------
__global__ __launch_bounds__(256) void k_pass1(const unsigned short* __restrict__ Kbf,
                                               const unsigned short* __restrict__ Qbf,
                                               float* __restrict__ invl) {
    __shared__ unsigned short KbS[128 * 64];  // 16KB, XOR-swizzled 16B slots
    __shared__ unsigned short QbS[64 * 64];   // 8KB
    int d0 = blockIdx.x * 128, b = blockIdx.y;
    int tid = threadIdx.x, lane = tid & 63, w = tid >> 6;
    int ln15 = lane & 15, lj = lane >> 4;
    for (int s = 0; s < 4; s++) {
        int idx = tid + 256 * s;
        int r = idx >> 3, c = idx & 7;
        short8 vv = *(const short8*)(Kbf + ((size_t)(b * VD + d0 + r)) * 64 + c * 8);
        *(short8*)&KbS[r * 64 + ((c ^ (r & 7)) << 3)] = vv;
    }
    __syncthreads();
    short8 A[2][2];
    #pragma unroll
    for (int dgi = 0; dgi < 2; dgi++) {
        int row = (w * 2 + dgi) * 16 + ln15;
        #pragma unroll
        for (int kg = 0; kg < 2; kg++)
            A[dgi][kg] = *(const short8*)&KbS[row * 64 + ((((kg << 2) + lj) ^ (row & 7)) << 3)];
    }
    float lacc[2][4] = {{0.f, 0.f, 0.f, 0.f}, {0.f, 0.f, 0.f, 0.f}};
    const f32x4 Z = {0.f, 0.f, 0.f, 0.f};
    for (int e0 = 0; e0 < VD; e0 += 64) {
        __syncthreads();
        for (int s = 0; s < 2; s++) {
            int idx = tid + 256 * s;
            int r = idx >> 3, c = idx & 7;
            short8 vv = *(const short8*)(Qbf + ((size_t)(b * VD + e0 + r)) * 64 + c * 8);
            *(short8*)&QbS[r * 64 + ((c ^ (r & 7)) << 3)] = vv;
        }
        __syncthreads();
        #pragma unroll
        for (int eg = 0; eg < 4; eg++) {
            int rowq = eg * 16 + ln15;
            short8 B0 = *(const short8*)&QbS[rowq * 64 + ((lj ^ (rowq & 7)) << 3)];
            short8 B1 = *(const short8*)&QbS[rowq * 64 + (((4 + lj) ^ (rowq & 7)) << 3)];
            #pragma unroll
            for (int dgi = 0; dgi < 2; dgi++) {
                f32x4 D = mfma16(A[dgi][0], B0, Z);
                D = mfma16(A[dgi][1], B1, D);
                #pragma unroll
                for (int r = 0; r < 4; r++) lacc[dgi][r] += __expf(D[r] * SCALE_V);
            }
        }
    }
    #pragma unroll
    for (int dgi = 0; dgi < 2; dgi++)
        #pragma unroll
        for (int r = 0; r < 4; r++) {
            float s = lacc[dgi][r];
            s += __shfl_xor(s, 1, 64); s += __shfl_xor(s, 2, 64);
            s += __shfl_xor(s, 4, 64); s += __shfl_xor(s, 8, 64);
            lacc[dgi][r] = s;
        }
    if (ln15 == 0) {
        #pragma unroll
        for (int dgi = 0; dgi < 2; dgi++)
            #pragma unroll
            for (int r = 0; r < 4; r++)
                invl[(size_t)b * VD + d0 + (w * 2 + dgi) * 16 + lj * 4 + r] = 1.f / lacc[dgi][r];
    }
}

// ---------- pass2: MFMA S (bf16) + fp32 PV, e-tile 128, d split in halves ----------
__global__ __launch_bounds__(128) void k_pass2(const unsigned short* __restrict__ Kbf,
                                               const unsigned short* __restrict__ Qbf,
                                               const float* __restrict__ Vis,
                                               const float* __restrict__ invl,
                                               float* __restrict__ Opart) {
    __shared__ unsigned short KbS[64 * 64];   // 8KB
    __shared__ unsigned short QbS[128 * 64];  // 16KB
    __shared__ float Vt[64 * 68];             // 17KB   Vt[d][n] = Vis[b][d][n]*invl[d], n pad 64
    __shared__ float Pl[64 * 132];            // 33.8KB
    int bx = blockIdx.x, b = blockIdx.y;
    int e0 = (bx & 15) * 128, half = bx >> 4;
    int tid = threadIdx.x, lane = tid & 63, w = tid >> 6;
    int ln15 = lane & 15, lj = lane >> 4;
    int ni = tid >> 4, ej = tid & 15;
    // stage Qb once (e-tile 128)
    for (int s = 0; s < 8; s++) {
        int idx = tid + 128 * s;
        int r = idx >> 3, c = idx & 7;
        short8 vv = *(const short8*)(Qbf + ((size_t)(b * VD + e0 + r)) * 64 + c * 8);
        *(short8*)&QbS[r * 64 + ((c ^ (r & 7)) << 3)] = vv;
    }
    float oacc[8][8];
    #pragma unroll
    for (int i = 0; i < 8; i++)
        #pragma unroll
        for (int j = 0; j < 8; j++) oacc[i][j] = 0.f;
    const f32x4 Z = {0.f, 0.f, 0.f, 0.f};

    for (int it = 0; it < 16; it++) {
        int d0 = half * 1024 + it * 64;
        __syncthreads();  // prev PV done (and Qb staged, iter 0)
        for (int s = 0; s < 4; s++) {
            int idx = tid + 128 * s;
            int r = idx >> 3, c = idx & 7;
            short8 vv = *(const short8*)(Kbf + ((size_t)(b * VD + d0 + r)) * 64 + c * 8);
            *(short8*)&KbS[r * 64 + ((c ^ (r & 7)) << 3)] = vv;
        }
        for (int s = 0; s < 32; s++) {
            int idx = tid + 128 * s;
            int r = idx >> 6, c = idx & 63;
            float val = 0.f;
            if (c < VN) val = Vis[((size_t)(b * VD + d0 + r)) * VN + c] * invl[(size_t)b * VD + d0 + r];
            Vt[r * 68 + c] = val;
        }
        __syncthreads();
        // S tile 64d x 128e via MFMA
        short8 A[2][2];
        #pragma unroll
        for (int dgi = 0; dgi < 2; dgi++) {
            int row = (w * 2 + dgi) * 16 + ln15;
            #pragma unroll
            for (int kg = 0; kg < 2; kg++)
                A[dgi][kg] = *(const short8*)&KbS[row * 64 + ((((kg << 2) + lj) ^ (row & 7)) << 3)];
        }
        #pragma unroll
        for (int eg = 0; eg < 8; eg++) {
            int rowq = eg * 16 + ln15;
            short8 B0 = *(const short8*)&QbS[rowq * 64 + ((lj ^ (rowq & 7)) << 3)];
            short8 B1 = *(const short8*)&QbS[rowq * 64 + (((4 + lj) ^ (rowq & 7)) << 3)];
            #pragma unroll
            for (int dgi = 0; dgi < 2; dgi++) {
                f32x4 D = mfma16(A[dgi][0], B0, Z);
                D = mfma16(A[dgi][1], B1, D);
                int rbase = (w * 2 + dgi) * 16 + lj * 4;
                int col = eg * 16 + ln15;
                #pragma unroll
                for (int r = 0; r < 4; r++)
                    Pl[(rbase + r) * 132 + col] = __expf(D[r] * SCALE_V);
            }
        }
        __syncthreads();
        // PV fp32: oacc[i][j] += Vt[dd][ni*8+i] * Pl[dd][ej*8+j]
        for (int dd = 0; dd < 64; dd++) {
            float4 va = *(const float4*)&Vt[dd * 68 + ni * 8];
            float4 vb = *(const float4*)&Vt[dd * 68 + ni * 8 + 4];
            float4 pa = *(const float4*)&Pl[dd * 132 + ej * 8];
            float4 pb = *(const float4*)&Pl[dd * 132 + ej * 8 + 4];
            float vv[8] = {va.x, va.y, va.z, va.w, vb.x, vb.y, vb.z, vb.w};
            float pp[8] = {pa.x, pa.y, pa.z, pa.w, pb.x, pb.y, pb.z, pb.w};
            #pragma unroll
            for (int i = 0; i < 8; i++)
                #pragma unroll
                for (int j = 0; j < 8; j++) oacc[i][j] += vv[i] * pp[j];
        }
    }
    #pragma unroll
    for (int i = 0; i < 8; i++) {
        int n = ni * 8 + i;
        if (n < VN) {
            float4 o0 = {oacc[i][0], oacc[i][1], oacc[i][2], oacc[i][3]};
            float4 o1 = {oacc[i][4], oacc[i][5], oacc[i][6], oacc[i][7]};
            size_t base = (size_t)half * 1605632 + ((size_t)(b * VN + n)) * VD + e0 + ej * 8;
            *(float4*)&Opart[base] = o0;
            *(float4*)&Opart[base + 4] = o1;
        }
    }
}

// ---------- sum the two d-half partials ----------
__global__ void k_osum(const float* __restrict__ Op, float* __restrict__ out) {
    int i = blockIdx.x * 256 + threadIdx.x;  // over 401408 float4s
    const float4* A = (const float4*)Op;
    float4 x = A[i], y = A[i + 401408];
    float4 r = {x.x + y.x, x.y + y.y, x.z + y.z, x.w + y.w};
    ((float4*)out)[i] = r;
}

// ---------- audio scores ----------
__global__ void k_scoresA(const float* __restrict__ Kk, const float* __restrict__ Qq,
                          float* __restrict__ S) {
    __shared__ __align__(16) float Kl[AN * AE];
    __shared__ __align__(16) float Ql[AN * AE];
    int b = blockIdx.x;
    int tid = threadIdx.x;
    int wave = tid >> 6, lane = tid & 63;
    const float* Kb = Kk + (size_t)b * AN * AE;
    const float* Qb = Qq + (size_t)b * AN * AE;
    for (int idx = tid; idx < AN * AE / 4; idx += 256) {
        *(float4*)&Kl[idx << 2] = *(const float4*)(Kb + (idx << 2));
        *(float4*)&Ql[idx << 2] = *(const float4*)(Qb + (idx << 2));
    }
    __syncthreads();
    for (int d2 = wave * 2; d2 < AE; d2 += 8) {
        float s00 = 0, s01 = 0, s10 = 0, s11 = 0;
        for (int n = 0; n < AN; n++) {
            float k0 = Kl[n * AE + d2];
            float k1 = Kl[n * AE + d2 + 1];
            float q0 = Ql[n * AE + lane];
            float q1 = Ql[n * AE + 64 + lane];
            s00 += k0 * q0; s01 += k0 * q1;
            s10 += k1 * q0; s11 += k1 * q1;
        }
        s00 *= SCALE_A; s01 *= SCALE_A; s10 *= SCALE_A; s11 *= SCALE_A;
        float mx = fmaxf(s00, s01);
        for (int o = 1; o < 64; o <<= 1) mx = fmaxf(mx, __shfl_xor(mx, o, 64));
        float e0v = __expf(s00 - mx), e1v = __expf(s01 - mx);
        float sm = e0v + e1v;
        for (int o = 1; o < 64; o <<= 1) sm += __shfl_xor(sm, o, 64);
        float inv = 1.f / sm;
        S[(size_t)b * AE * AE + (size_t)d2 * AE + lane] = e0v * inv;
        S[(size_t)b * AE * AE + (size_t)d2 * AE + 64 + lane] = e1v * inv;
        mx = fmaxf(s10, s11);
        for (int o = 1; o < 64; o <<= 1) mx = fmaxf(mx, __shfl_xor(mx, o, 64));
        e0v = __expf(s10 - mx); e1v = __expf(s11 - mx);
        sm = e0v + e1v;
        for (int o = 1; o < 64; o <<= 1) sm += __shfl_xor(sm, o, 64);
        inv = 1.f / sm;
        S[(size_t)b * AE * AE + (size_t)(d2 + 1) * AE + lane] = e0v * inv;
        S[(size_t)b * AE * AE + (size_t)(d2 + 1) * AE + 64 + lane] = e1v * inv;
    }
}

// ---------- a_out: LDS-staged A, coalesced S, 64 blocks ----------
__global__ void k_aout(const float* __restrict__ a, const float* __restrict__ S,
                       float* __restrict__ out) {
    __shared__ float al[16 * 132];
    int nc = blockIdx.x, b = blockIdx.y;
    int tid = threadIdx.x;  // 256
    for (int s = 0; s < 8; s++) {
        int idx = tid + 256 * s;
        int n = idx >> 7, d = idx & 127;
        al[n * 132 + d] = a[((size_t)(b * AN + nc * 16 + n)) * AE + d];
    }
    __syncthreads();
    int e = tid & 127, g = tid >> 7;
    const float* Sb = S + (size_t)b * AE * AE;
    float o[8] = {0, 0, 0, 0, 0, 0, 0, 0};
    for (int d = 0; d < AE; d++) {
        float s = Sb[d * AE + e];
        #pragma unroll
        for (int i = 0; i < 8; i++) o[i] += al[(g * 8 + i) * 132 + d] * s;
    }
    #pragma unroll
    for (int i = 0; i < 8; i++)
        out[((size_t)(b * AN + nc * 16 + g * 8 + i)) * AE + e] = o[i];
}

extern "C" void kernel_launch(void* const* d_in, const int* in_sizes, int n_in,
                              void* d_out, int out_size, void* d_ws, size_t ws_size,
                              hipStream_t stream) {
    const float* Vis  = (const float*)d_in[0];
    const float* Aud  = (const float*)d_in[1];
    const float* aW1  = (const float*)d_in[2];
    const float* ab1  = (const float*)d_in[3];
    const float* a_g1 = (const float*)d_in[4];
    const float* a_b1 = (const float*)d_in[5];
    const float* aW2  = (const float*)d_in[6];
    const float* ab2  = (const float*)d_in[7];
    const float* vW1  = (const float*)d_in[8];
    const float* vb1  = (const float*)d_in[9];
    const float* v_g1 = (const float*)d_in[10];
    const float* v_b1 = (const float*)d_in[11];
    const float* vW2  = (const float*)d_in[12];
    const float* vb2  = (const float*)d_in[13];
    const float* kaW  = (const float*)d_in[14];
    const float* kab  = (const float*)d_in[15];
    const float* ka_g = (const float*)d_in[16];
    const float* ka_b = (const float*)d_in[17];
    const float* kvW  = (const float*)d_in[18];
    const float* kvb  = (const float*)d_in[19];
    const float* kv_g = (const float*)d_in[20];
    const float* kv_b = (const float*)d_in[21];

    float* ws = (float*)d_ws;
    float* v       = ws;                        // 1,605,632
    float* vquery  = ws + 1605632;              // 1,605,632
    float* vkeys   = ws + 2 * 1605632;          // 1,605,632
    float* Opart   = vquery;                    // alias: 2x1,605,632 over vquery+vkeys (dead after preps)
    float* vhbuf   = ws + 3 * 1605632;          // 38,416
    float* xa      = vhbuf + 38416;             // 65,536
    float* aquery  = xa + 65536;                // 131,072
    float* akeys   = aquery + 131072;           // 131,072
    float* scoresA = akeys + 131072;            // 262,144
    float* invl    = scoresA + 262144;          // 32,768
    float* stats   = invl + 32768;              // 512
    unsigned short* Qbf = (unsigned short*)(stats + 512);       // 2,097,152 ushorts
    unsigned short* Kbf = Qbf + 2097152;                        // 2,097,152 ushorts
    // total ~30.3 MB

    float* vout = (float*)d_out;                // (16,49,2048)
    float* aout = vout + 1605632;               // (16,64,128)

    // vision transpose (needed by vh/vkeys paths)
    k_transpose<<<dim3(64, 2, 16), dim3(32, 8), 0, stream>>>(Vis, v);

    // audio query MLP
    k_xa<<<256, 256, 0, stream>>>(Aud, aW1, ab1, xa);
    k_bnstats<<<64, 256, 0, stream>>>(xa, 64, 64, a_g1, a_b1, stats + 0, stats + 64);
    k_aquery<<<NB * AN, 128, 0, stream>>>(xa, aW2, ab2, stats + 0, stats + 64, aquery);

    // audio keys
    k_akeys<<<512, 256, 0, stream>>>(Aud, kaW, kab, akeys);
    k_bnstats<<<64, 256, 0, stream>>>(akeys, 64, 128, ka_g, ka_b, stats + 128, stats + 192);
    k_bnapply<<<512, 256, 0, stream>>>(akeys, 64, 128, stats + 128, stats + 192, 131072);

    // vision query MLP
    k_vh<<<NB * VN, 64, 0, stream>>>(v, vW1, vb1, vhbuf);
    k_bnstats<<<49, 256, 0, stream>>>(vhbuf, 49, 49, v_g1, v_b1, stats + 256, stats + 320);
    k_bnapply<<<(38416 + 255) / 256, 256, 0, stream>>>(vhbuf, 49, 49, stats + 256, stats + 320, 38416);
    k_vquery<<<NB * VN, 256, 0, stream>>>(vhbuf, vW2, vb2, vquery);

    // vision keys pre-BN + stats
    k_vkeys<<<6272, 256, 0, stream>>>(v, kvW, kvb, vkeys);
    k_bnstats<<<49, 256, 0, stream>>>(vkeys, 49, 2048, kv_g, kv_b, stats + 384, stats + 448);

    // prep bf16 transposed operands (k padded to 64; BN+relu folded into K)
    k_prepQ<<<dim3(32, 16), 256, 0, stream>>>(vquery, Qbf);
    k_prepK<<<dim3(32, 16), 256, 0, stream>>>(vkeys, stats + 384, stats + 448, Kbf);

    // vision attention
    k_pass1<<<dim3(16, 16), 256, 0, stream>>>(Kbf, Qbf, invl);
    k_pass2<<<dim3(32, 16), 128, 0, stream>>>(Kbf, Qbf, Vis, invl, Opart);
    k_osum<<<1568, 256, 0, stream>>>(Opart, vout);

    // audio attention
    k_scoresA<<<16, 256, 0, stream>>>(akeys, aquery, scoresA);
    k_aout<<<dim3(4, 16), 256, 0, stream>>>(Aud, scoresA, aout);
}

// Round 6
// 362.510 us; speedup vs baseline: 2.2922x; 1.7490x over previous
//
#include <hip/hip_runtime.h>
#include <math.h>

#define NB 16
#define VN 49
#define VD 2048
#define AN 64
#define AE 128
#define AH 64
#define EPS 1e-5f
#define SCALE_V 0.022097086912079608f  // 1/sqrt(2048)
#define SCALE_A 0.08838834764831845f   // 1/sqrt(128)

typedef __attribute__((ext_vector_type(8))) short short8;
typedef __attribute__((ext_vector_type(8))) __bf16 bf16x8;
typedef __attribute__((ext_vector_type(4))) float f32x4;

__device__ __forceinline__ f32x4 mfma16(short8 a, short8 b, f32x4 c) {
    return __builtin_amdgcn_mfma_f32_16x16x32_bf16(
        __builtin_bit_cast(bf16x8, a), __builtin_bit_cast(bf16x8, b), c, 0, 0, 0);
}

__device__ __forceinline__ unsigned short f2bf(float x) {
    unsigned int u = __builtin_bit_cast(unsigned int, x);
    unsigned int r = (u + 0x7fffu + ((u >> 16) & 1u)) >> 16;  // RNE
    return (unsigned short)r;
}

// ======================= role device functions =======================

// v[b][n][d] = Vis[b][d][n]
__device__ void r_transpose(int bb, const float* __restrict__ Vis, float* __restrict__ v, void* sm) {
    float (*t)[33] = (float(*)[33])sm;
    int x = bb & 63, y = (bb >> 6) & 1, b = bb >> 7;
    int d0 = x * 32, n0 = y * 32;
    int tid = threadIdx.x, tx = tid & 31, ty = tid >> 5;
    for (int k = 0; k < 4; k++) {
        int d = d0 + ty + 8 * k, n = n0 + tx;
        float val = 0.f;
        if (n < VN) val = Vis[(size_t)b * VD * VN + (size_t)d * VN + n];
        t[ty + 8 * k][tx] = val;
    }
    __syncthreads();
    for (int k = 0; k < 4; k++) {
        int n = n0 + ty + 8 * k, d = d0 + tx;
        if (n < VN) v[(size_t)b * VN * VD + (size_t)n * VD + d] = t[tx][ty + 8 * k];
    }
}

__device__ void r_xa(int bb, const float* __restrict__ a, const float* __restrict__ aW1,
                     const float* __restrict__ ab1, float* __restrict__ xa) {
    int idx = bb * 256 + threadIdx.x;  // 65536
    int h = idx & (AH - 1);
    int bn = idx >> 6;
    const float* ar = a + (size_t)bn * AE;
    const float* wr = aW1 + (size_t)h * AE;
    float s = ab1[h];
    for (int d = 0; d < AE; d += 4) {
        float4 w = *(const float4*)(wr + d);
        float4 av = *(const float4*)(ar + d);
        s += av.x * w.x + av.y * w.y + av.z * w.z + av.w * w.w;
    }
    xa[idx] = s;
}

__device__ void r_akeys(int bb, const float* __restrict__ a, const float* __restrict__ kaW,
                        const float* __restrict__ kab, float* __restrict__ ak) {
    int idx = bb * 256 + threadIdx.x;  // 131072
    int d = idx & (AE - 1);
    int bo = idx >> 7;
    int o = bo & (AN - 1);
    int b = bo >> 6;
    float s = kab[o];
    const float* ap = a + (size_t)b * AN * AE + d;
    const float* wr = kaW + (size_t)o * AN;
    for (int n = 0; n < AN; n++) s += wr[n] * ap[(size_t)n * AE];
    ak[idx] = s;
}

// stats reduction: red = 512 floats of LDS
__device__ void red_stats(float s, float s2, int c, int N, const float* __restrict__ g,
                          const float* __restrict__ beta, float* __restrict__ scale,
                          float* __restrict__ shift, float* red) {
    int tid = threadIdx.x;
    red[tid] = s; red[256 + tid] = s2;
    __syncthreads();
    for (int o = 128; o > 0; o >>= 1) {
        if (tid < o) { red[tid] += red[tid + o]; red[256 + tid] += red[256 + tid + o]; }
        __syncthreads();
    }
    if (tid == 0) {
        float mean = red[0] / N;
        float var = red[256] / N - mean * mean;
        float sc = g[c] * rsqrtf(var + EPS);
        scale[c] = sc;
        shift[c] = beta[c] - mean * sc;
    }
}

__device__ void r_bnst_a1(int c, const float* __restrict__ xa, const float* __restrict__ g,
                          const float* __restrict__ beta, float* __restrict__ stats, void* sm) {
    int tid = threadIdx.x;  // 256 f4 = 1024 floats, L=64
    int b = tid >> 4, l = (tid & 15) << 2;
    float4 x = *(const float4*)(xa + ((size_t)(b * 64 + c)) * 64 + l);
    float s = x.x + x.y + x.z + x.w;
    float s2 = x.x * x.x + x.y * x.y + x.z * x.z + x.w * x.w;
    red_stats(s, s2, c, 1024, g, beta, stats + 0, stats + 64, (float*)sm);
}

__device__ void r_bnst_ka(int c, const float* __restrict__ ak, const float* __restrict__ g,
                          const float* __restrict__ beta, float* __restrict__ stats, void* sm) {
    int tid = threadIdx.x;  // 512 f4 = 2048 floats, L=128
    float s = 0.f, s2 = 0.f;
    for (int p = 0; p < 2; p++) {
        int f = tid + 256 * p;
        int b = f >> 5, l = (f & 31) << 2;
        float4 x = *(const float4*)(ak + ((size_t)(b * 64 + c)) * 128 + l);
        s += x.x + x.y + x.z + x.w;
        s2 += x.x * x.x + x.y * x.y + x.z * x.z + x.w * x.w;
    }
    red_stats(s, s2, c, 2048, g, beta, stats + 128, stats + 192, (float*)sm);
}

__device__ void r_bnst_v1(int c, const float* __restrict__ vh, const float* __restrict__ g,
                          const float* __restrict__ beta, float* __restrict__ stats, void* sm) {
    int tid = threadIdx.x;
    float s = 0.f, s2 = 0.f;
    if (tid < VN) {
        for (int b = 0; b < NB; b++) {
            float x = vh[((size_t)(b * VN + c)) * VN + tid];
            s += x; s2 += x * x;
        }
    }
    red_stats(s, s2, c, NB * VN, g, beta, stats + 256, stats + 320, (float*)sm);
}

__device__ void r_bnst_kv(int c, const float* __restrict__ vk, const float* __restrict__ g,
                          const float* __restrict__ beta, float* __restrict__ stats, void* sm) {
    int tid = threadIdx.x;
    float s = 0.f, s2 = 0.f;
    for (int b = 0; b < NB; b++) {
        for (int p = 0; p < 2; p++) {
            int f = tid + 256 * p;
            float4 x = *(const float4*)(vk + ((size_t)(b * VN + c)) * VD + (f << 2));
            s += x.x + x.y + x.z + x.w;
            s2 += x.x * x.x + x.y * x.y + x.z * x.z + x.w * x.w;
        }
    }
    red_stats(s, s2, c, NB * VD, g, beta, stats + 384, stats + 448, (float*)sm);
}

__device__ void r_vh(int bn, const float* __restrict__ v, const float* __restrict__ vW1,
                     const float* __restrict__ vb1, float* __restrict__ vh, void* sm) {
    float* vl = (float*)sm;        // 2048
    float* part = vl + 2048;       // 256
    int tid = threadIdx.x;
    const float* vr = v + (size_t)bn * VD;
    for (int s = 0; s < 2; s++) {
        int i4 = tid + 256 * s;
        *(float4*)&vl[i4 << 2] = *(const float4*)(vr + (i4 << 2));
    }
    __syncthreads();
    int h = tid & 63, p = tid >> 6;
    float s = 0.f;
    if (h < VN) {
        const float* wr = vW1 + (size_t)h * VD + p * 512;
        const float* vp = vl + p * 512;
        for (int d = 0; d < 512; d += 4) {
            float4 w = *(const float4*)(wr + d);
            s += vp[d] * w.x + vp[d + 1] * w.y + vp[d + 2] * w.z + vp[d + 3] * w.w;
        }
    }
    part[p * 64 + h] = s;
    __syncthreads();
    if (tid < VN)
        vh[(size_t)bn * VN + tid] = vb1[tid] + part[tid] + part[64 + tid] + part[128 + tid] + part[192 + tid];
}

__device__ void r_vkeys(int bb, const float* __restrict__ v, const float* __restrict__ kvW,
                        const float* __restrict__ kvb, float* __restrict__ vk) {
    int idx = bb * 256 + threadIdx.x;  // 16*49*2048
    int d = idx & (VD - 1);
    int bo = idx >> 11;
    int o = bo % VN;
    int b = bo / VN;
    float s = kvb[o];
    const float* vp = v + (size_t)b * VN * VD + d;
    const float* wr = kvW + (size_t)o * VN;
    for (int n = 0; n < VN; n++) s += wr[n] * vp[(size_t)n * VD];
    vk[idx] = s;
}

__device__ void r_aquery(int bb, const float* __restrict__ xa, const float* __restrict__ aW2,
                         const float* __restrict__ ab2, const float* __restrict__ stats,
                         float* __restrict__ aq, void* sm) {
    float* ah = (float*)sm;  // [2][64]
    int tid = threadIdx.x;
    int half = tid >> 7, t = tid & 127;
    int bn = bb * 2 + half;
    int n = bn & (AN - 1);
    if (t < AH) ah[half * 64 + t] = fmaxf(xa[(size_t)bn * AH + t] * stats[n] + stats[64 + n], 0.f);
    __syncthreads();
    float s = ab2[t];
    const float* wr = aW2 + (size_t)t * AH;
    for (int h = 0; h < AH; h++) s += ah[half * 64 + h] * wr[h];
    aq[(size_t)bn * AE + t] = s;
}

__device__ void r_vquery(int bn, const float* __restrict__ vh, const float* __restrict__ stats,
                         const float* __restrict__ vW2, const float* __restrict__ vb2,
                         float* __restrict__ vq, void* sm) {
    float* hl = (float*)sm;  // 49
    int t = threadIdx.x;
    // BN channel is the TOKEN index n (dim 1 of (B,n,h)), one scalar per row.
    int n = bn % VN;
    float scn = stats[256 + n], shn = stats[320 + n];
    if (t < VN) hl[t] = fmaxf(vh[(size_t)bn * VN + t] * scn + shn, 0.f);
    __syncthreads();
    for (int d = t; d < VD; d += 256) {
        const float* wr = vW2 + (size_t)d * VN;
        float s = vb2[d];
        for (int h = 0; h < VN; h++) s += hl[h] * wr[h];
        vq[(size_t)bn * VD + d] = s;
    }
}

// vquery[b][k][e] -> Qbf[b][e][k64] bf16, k padded 49->64
__device__ void r_prepQ(int bb, const float* __restrict__ vq, unsigned short* __restrict__ Qbf, void* sm) {
    unsigned short* T = (unsigned short*)sm;  // [64][72]
    int dt = bb & 31, b = bb >> 5;
    int tid = threadIdx.x;
    for (int s = 0; s < 16; s++) {
        int idx = tid + 256 * s;
        int dl = idx & 63, n = idx >> 6;
        float val = (n < VN) ? vq[((size_t)(b * VN + n)) * VD + dt * 64 + dl] : 0.f;
        T[dl * 72 + n] = f2bf(val);
    }
    __syncthreads();
    for (int s = 0; s < 2; s++) {
        int idx = tid + 256 * s;
        int r = idx >> 3, c = idx & 7;
        short8 vv = *(const short8*)&T[r * 72 + c * 8];
        *(short8*)(Qbf + ((size_t)(b * VD + dt * 64 + r)) * 64 + c * 8) = vv;
    }
}

// vkeys + BN + relu -> Kbf[b][d][k64] bf16
__device__ void r_prepK(int bb, const float* __restrict__ vk, const float* __restrict__ stats,
                        unsigned short* __restrict__ Kbf, void* sm) {
    unsigned short* T = (unsigned short*)sm;  // [64][72]
    int dt = bb & 31, b = bb >> 5;
    int tid = threadIdx.x;
    for (int s = 0; s < 16; s++) {
        int idx = tid + 256 * s;
        int dl = idx & 63, n = idx >> 6;
        float val = 0.f;
        if (n < VN) {
            float x = vk[((size_t)(b * VN + n)) * VD + dt * 64 + dl];
            val = fmaxf(x * stats[384 + n] + stats[448 + n], 0.f);
        }
        T[dl * 72 + n] = f2bf(val);
    }
    __syncthreads();
    for (int s = 0; s < 2; s++) {
        int idx = tid + 256 * s;
        int r = idx >> 3, c = idx & 7;
        short8 vv = *(const short8*)&T[r * 72 + c * 8];
        *(short8*)(Kbf + ((size_t)(b * VD + dt * 64 + r)) * 64 + c * 8) = vv;
    }
}

// Vis[b][d][n] -> Vbf[b][n64][d] bf16 (rows n>=49 zero)
__device__ void r_prepV(int bb, const float* __restrict__ Vis, unsigned short* __restrict__ Vbf, void* sm) {
    float* T = (float*)sm;  // [64][65]
    int dt = bb & 31, b = bb >> 5;
    int tid = threadIdx.x;
    for (int s = 0; s < 16; s++) {
        int idx = tid + 256 * s;
        int n = idx & 63, dl = idx >> 6;
        float val = (n < VN) ? Vis[((size_t)(b * VD + dt * 64 + dl)) * VN + n] : 0.f;
        T[n * 65 + dl] = val;
    }
    __syncthreads();
    for (int s = 0; s < 4; s++) {
        int idx = tid + 256 * s;
        int n = idx >> 4, d4 = (idx & 15) << 2;
        ushort4 u;
        u.x = f2bf(T[n * 65 + d4]);     u.y = f2bf(T[n * 65 + d4 + 1]);
        u.z = f2bf(T[n * 65 + d4 + 2]); u.w = f2bf(T[n * 65 + d4 + 3]);
        *(ushort4*)(Vbf + ((size_t)(b * 64 + n)) * VD + dt * 64 + d4) = u;
    }
}

// audio scores, BN of akeys inline, Q read from global (L2-resident)
__device__ void r_scoresA(int b, const float* __restrict__ ak, const float* __restrict__ stats,
                          const float* __restrict__ aq, float* __restrict__ S, void* sm) {
    float* Kl = (float*)sm;  // [64][128]
    int tid = threadIdx.x;
    int wave = tid >> 6, lane = tid & 63;
    for (int s = 0; s < 8; s++) {
        int f = tid + 256 * s;
        int o = f >> 5, d4 = (f & 31) << 2;
        float4 x = *(const float4*)(ak + ((size_t)(b * AN + o)) * AE + d4);
        float sc = stats[128 + o], sh = stats[192 + o];
        float4 y;
        y.x = fmaxf(x.x * sc + sh, 0.f); y.y = fmaxf(x.y * sc + sh, 0.f);
        y.z = fmaxf(x.z * sc + sh, 0.f); y.w = fmaxf(x.w * sc + sh, 0.f);
        *(float4*)&Kl[o * AE + d4] = y;
    }
    __syncthreads();
    const float* Qb = aq + (size_t)b * AN * AE;
    for (int d2 = wave * 2; d2 < AE; d2 += 8) {
        float s00 = 0, s01 = 0, s10 = 0, s11 = 0;
        #pragma unroll 8
        for (int n = 0; n < AN; n++) {
            float k0 = Kl[n * AE + d2];
            float k1 = Kl[n * AE + d2 + 1];
            float q0 = Qb[n * AE + lane];
            float q1 = Qb[n * AE + 64 + lane];
            s00 += k0 * q0; s01 += k0 * q1;
            s10 += k1 * q0; s11 += k1 * q1;
        }
        s00 *= SCALE_A; s01 *= SCALE_A; s10 *= SCALE_A; s11 *= SCALE_A;
        float mx = fmaxf(s00, s01);
        for (int o = 1; o < 64; o <<= 1) mx = fmaxf(mx, __shfl_xor(mx, o, 64));
        float e0v = __expf(s00 - mx), e1v = __expf(s01 - mx);
        float smm = e0v + e1v;
        for (int o = 1; o < 64; o <<= 1) smm += __shfl_xor(smm, o, 64);
        float inv = 1.f / smm;
        S[(size_t)b * AE * AE + (size_t)d2 * AE + lane] = e0v * inv;
        S[(size_t)b * AE * AE + (size_t)d2 * AE + 64 + lane] = e1v * inv;
        mx = fmaxf(s10, s11);
        for (int o = 1; o < 64; o <<= 1) mx = fmaxf(mx, __shfl_xor(mx, o, 64));
        e0v = __expf(s10 - mx); e1v = __expf(s11 - mx);
        smm = e0v + e1v;
        for (int o = 1; o < 64; o <<= 1) smm += __shfl_xor(smm, o, 64);
        inv = 1.f / smm;
        S[(size_t)b * AE * AE + (size_t)(d2 + 1) * AE + lane] = e0v * inv;
        S[(size_t)b * AE * AE + (size_t)(d2 + 1) * AE + 64 + lane] = e1v * inv;
    }
}

__device__ void r_aout(int bb, const float* __restrict__ a, const float* __restrict__ S,
                       float* __restrict__ out, void* sm) {
    float* al = (float*)sm;  // [16][132]
    int nc = bb & 3, b = bb >> 2;
    int tid = threadIdx.x;
    for (int s = 0; s < 8; s++) {
        int idx = tid + 256 * s;
        int n = idx >> 7, d = idx & 127;
        al[n * 132 + d] = a[((size_t)(b * AN + nc * 16 + n)) * AE + d];
    }
    __syncthreads();
    int e = tid & 127, g = tid >> 7;
    const float* Sb = S + (size_t)b * AE * AE;
    float o[8] = {0, 0, 0, 0, 0, 0, 0, 0};
    for (int d = 0; d < AE; d++) {
        float s = Sb[d * AE + e];
        #pragma unroll
        for (int i = 0; i < 8; i++) o[i] += al[(g * 8 + i) * 132 + d] * s;
    }
    #pragma unroll
    for (int i = 0; i < 8; i++)
        out[((size_t)(b * AN + nc * 16 + g * 8 + i)) * AE + e] = o[i];
}

// ======================= phase kernels =======================

__global__ __launch_bounds__(256) void F1(const float* __restrict__ Vis, const float* __restrict__ Aud,
                                          const float* __restrict__ aW1, const float* __restrict__ ab1,
                                          const float* __restrict__ kaW, const float* __restrict__ kab,
                                          float* __restrict__ v, float* __restrict__ xa,
                                          float* __restrict__ ak) {
    __shared__ __align__(16) char sm[4352];
    int bb = blockIdx.x;
    if (bb < 2048) r_transpose(bb, Vis, v, sm);
    else if (bb < 2304) r_xa(bb - 2048, Aud, aW1, ab1, xa);
    else r_akeys(bb - 2304, Aud, kaW, kab, ak);
}

__global__ __launch_bounds__(256) void F2(const float* __restrict__ v, const float* __restrict__ vW1,
                                          const float* __restrict__ vb1, float* __restrict__ vh,
                                          const float* __restrict__ kvW, const float* __restrict__ kvb,
                                          float* __restrict__ vk, const float* __restrict__ xa,
                                          const float* __restrict__ a_g1, const float* __restrict__ a_b1,
                                          const float* __restrict__ ak, const float* __restrict__ ka_g,
                                          const float* __restrict__ ka_b, float* __restrict__ stats) {
    __shared__ __align__(16) char sm[9216];
    int bb = blockIdx.x;
    if (bb < 784) r_vh(bb, v, vW1, vb1, vh, sm);
    else if (bb < 7056) r_vkeys(bb - 784, v, kvW, kvb, vk);
    else if (bb < 7120) r_bnst_a1(bb - 7056, xa, a_g1, a_b1, stats, sm);
    else r_bnst_ka(bb - 7120, ak, ka_g, ka_b, stats, sm);
}

__global__ __launch_bounds__(256) void F3(const float* __restrict__ vh, const float* __restrict__ v_g1,
                                          const float* __restrict__ v_b1, const float* __restrict__ vk,
                                          const float* __restrict__ kv_g, const float* __restrict__ kv_b,
                                          float* __restrict__ stats, const float* __restrict__ xa,
                                          const float* __restrict__ aW2, const float* __restrict__ ab2,
                                          float* __restrict__ aq) {
    __shared__ __align__(16) char sm[2048];
    int bb = blockIdx.x;
    if (bb < 49) r_bnst_v1(bb, vh, v_g1, v_b1, stats, sm);
    else if (bb < 98) r_bnst_kv(bb - 49, vk, kv_g, kv_b, stats, sm);
    else r_aquery(bb - 98, xa, aW2, ab2, stats, aq, sm);
}

__global__ __launch_bounds__(256) void F4(const float* __restrict__ vh, const float* __restrict__ stats,
                                          const float* __restrict__ vW2, const float* __restrict__ vb2,
                                          float* __restrict__ vq, const float* __restrict__ vk,
                                          unsigned short* __restrict__ Kbf, const float* __restrict__ ak,
                                          const float* __restrict__ aq, float* __restrict__ S) {
    __shared__ __align__(16) char sm[32768];
    int bb = blockIdx.x;
    if (bb < 784) r_vquery(bb, vh, stats, vW2, vb2, vq, sm);
    else if (bb < 1296) r_prepK(bb - 784, vk, stats, Kbf, sm);
    else r_scoresA(bb - 1296, ak, stats, aq, S, sm);
}

__global__ __launch_bounds__(256) void F5(const float* __restrict__ vq, unsigned short* __restrict__ Qbf,
                                          const float* __restrict__ Aud, const float* __restrict__ S,
                                          float* __restrict__ aout, const float* __restrict__ Vis,
                                          unsigned short* __restrict__ Vbf) {
    __shared__ __align__(16) char sm[16640];
    int bb = blockIdx.x;
    if (bb < 512) r_prepQ(bb, vq, Qbf, sm);
    else if (bb < 576) r_aout(bb - 512, Aud, S, aout, sm);
    else r_prepV(bb - 576, Vis, Vbf, sm);
}

// ---------- pass1: invl[b][d] = 1/sum_e exp(SCALE_V * S[d][e]) ----------
__global__ __launch_bounds__(256) void k_pass1(const unsigned short* __restrict__ Kbf,
                                               const unsigned short* __restrict__ Qbf,
                                               float* __restrict__ invl) {
    __shared__ unsigned short KbS[128 * 64];
    __shared__ unsigned short QbS[64 * 64];
    int d0 = blockIdx.x * 128, b = blockIdx.y;
    int tid = threadIdx.x, lane = tid & 63, w = tid >> 6;
    int ln15 = lane & 15, lj = lane >> 4;
    for (int s = 0; s < 4; s++) {
        int idx = tid + 256 * s;
        int r = idx >> 3, c = idx & 7;
        short8 vv = *(const short8*)(Kbf + ((size_t)(b * VD + d0 + r)) * 64 + c * 8);
        *(short8*)&KbS[r * 64 + ((c ^ (r & 7)) << 3)] = vv;
    }
    __syncthreads();
    short8 A[2][2];
    #pragma unroll
    for (int dgi = 0; dgi < 2; dgi++) {
        int row = (w * 2 + dgi) * 16 + ln15;
        #pragma unroll
        for (int kg = 0; kg < 2; kg++)
            A[dgi][kg] = *(const short8*)&KbS[row * 64 + ((((kg << 2) + lj) ^ (row & 7)) << 3)];
    }
    float lacc[2][4] = {{0.f, 0.f, 0.f, 0.f}, {0.f, 0.f, 0.f, 0.f}};
    const f32x4 Z = {0.f, 0.f, 0.f, 0.f};
    for (int e0 = 0; e0 < VD; e0 += 64) {
        __syncthreads();
        for (int s = 0; s < 2; s++) {
            int idx = tid + 256 * s;
            int r = idx >> 3, c = idx & 7;
            short8 vv = *(const short8*)(Qbf + ((size_t)(b * VD + e0 + r)) * 64 + c * 8);
            *(short8*)&QbS[r * 64 + ((c ^ (r & 7)) << 3)] = vv;
        }
        __syncthreads();
        #pragma unroll
        for (int eg = 0; eg < 4; eg++) {
            int rowq = eg * 16 + ln15;
            short8 B0 = *(const short8*)&QbS[rowq * 64 + ((lj ^ (rowq & 7)) << 3)];
            short8 B1 = *(const short8*)&QbS[rowq * 64 + (((4 + lj) ^ (rowq & 7)) << 3)];
            #pragma unroll
            for (int dgi = 0; dgi < 2; dgi++) {
                f32x4 D = mfma16(A[dgi][0], B0, Z);
                D = mfma16(A[dgi][1], B1, D);
                #pragma unroll
                for (int r = 0; r < 4; r++) lacc[dgi][r] += __expf(D[r] * SCALE_V);
            }
        }
    }
    #pragma unroll
    for (int dgi = 0; dgi < 2; dgi++)
        #pragma unroll
        for (int r = 0; r < 4; r++) {
            float s = lacc[dgi][r];
            s += __shfl_xor(s, 1, 64); s += __shfl_xor(s, 2, 64);
            s += __shfl_xor(s, 4, 64); s += __shfl_xor(s, 8, 64);
            lacc[dgi][r] = s;
        }
    if (ln15 == 0) {
        #pragma unroll
        for (int dgi = 0; dgi < 2; dgi++)
            #pragma unroll
            for (int r = 0; r < 4; r++)
                invl[(size_t)b * VD + d0 + (w * 2 + dgi) * 16 + lj * 4 + r] = 1.f / lacc[dgi][r];
    }
}

// ---------- pass2: full-MFMA (S bf16 + PV bf16 via transposed P in LDS) ----------
__global__ __launch_bounds__(256) void k_pass2(const unsigned short* __restrict__ Kbf,
                                               const unsigned short* __restrict__ Qbf,
                                               const unsigned short* __restrict__ Vbf,
                                               const float* __restrict__ invl,
                                               float* __restrict__ Out) {
    __shared__ unsigned short QbS[64 * 64];  // [e][k]  8KB
    __shared__ unsigned short KbS[64 * 64];  // [d][k]  8KB
    __shared__ unsigned short VbS[64 * 64];  // [n][dl] 8KB
    __shared__ unsigned short PT[64 * 64];   // [e][dl] 8KB
    __shared__ float il[64];
    int e0 = blockIdx.x * 64, b = blockIdx.y;
    int tid = threadIdx.x, lane = tid & 63, w = tid >> 6;
    int l15 = lane & 15, lj = lane >> 4;
    // stage Q once
    for (int s = 0; s < 2; s++) {
        int idx = tid + 256 * s;
        int r = idx >> 3, c = idx & 7;
        short8 vv = *(const short8*)(Qbf + ((size_t)(b * VD + e0 + r)) * 64 + c * 8);
        *(short8*)&QbS[r * 64 + ((c ^ (r & 7)) << 3)] = vv;
    }
    __syncthreads();
    short8 qf[4][2];
    #pragma unroll
    for (int et = 0; et < 4; et++) {
        int rq = et * 16 + l15;
        qf[et][0] = *(const short8*)&QbS[rq * 64 + ((lj ^ (rq & 7)) << 3)];
        qf[et][1] = *(const short8*)&QbS[rq * 64 + (((4 + lj) ^ (rq & 7)) << 3)];
    }
    f32x4 oa[4];
    const f32x4 Z = {0.f, 0.f, 0.f, 0.f};
    #pragma unroll
    for (int et = 0; et < 4; et++) oa[et] = Z;
    int rowA = w * 16 + l15;     // K/V row for A-frags
    int swA = rowA & 7;
    int dl = w * 16 + lj * 4;    // this lane's 4 S/P d-rows
    int dlo = dl & 7;            // 0 or 4
    int dsl = dl >> 3;

    for (int it = 0; it < 32; it++) {
        int d0 = it * 64;
        __syncthreads();  // prev-iter PT/VbS reads done (1st iter: after qf reads)
        for (int s = 0; s < 2; s++) {
            int idx = tid + 256 * s;
            int r = idx >> 3, c = idx & 7;
            short8 kv = *(const short8*)(Kbf + ((size_t)(b * VD + d0 + r)) * 64 + c * 8);
            *(short8*)&KbS[r * 64 + ((c ^ (r & 7)) << 3)] = kv;
            short8 vv = *(const short8*)(Vbf + ((size_t)(b * 64 + r)) * VD + d0 + c * 8);
            *(short8*)&VbS[r * 64 + ((c ^ (r & 7)) << 3)] = vv;
        }
        if (tid < 64) il[tid] = invl[(size_t)b * VD + d0 + tid];
        __syncthreads();
        // ---- S phase: wave w computes S rows [w*16, w*16+16) x e-tile 64
        short8 af0 = *(const short8*)&KbS[rowA * 64 + ((lj ^ swA) << 3)];
        short8 af1 = *(const short8*)&KbS[rowA * 64 + (((4 + lj) ^ swA) << 3)];
        float i0 = il[dl], i1 = il[dl + 1], i2 = il[dl + 2], i3 = il[dl + 3];
        #pragma unroll
        for (int et = 0; et < 4; et++) {
            f32x4 D = mfma16(af0, qf[et][0], Z);
            D = mfma16(af1, qf[et][1], D);
            ushort4 u;
            u.x = f2bf(__expf(D[0] * SCALE_V) * i0);
            u.y = f2bf(__expf(D[1] * SCALE_V) * i1);
            u.z = f2bf(__expf(D[2] * SCALE_V) * i2);
            u.w = f2bf(__expf(D[3] * SCALE_V) * i3);
            int e = et * 16 + l15;
            *(ushort4*)&PT[e * 64 + ((dsl ^ (e & 7)) << 3) + dlo] = u;
        }
        __syncthreads();
        // ---- PV phase: O[n = w*16+..][e] += V[n][dl]·P[dl][e]
        short8 vf0 = *(const short8*)&VbS[rowA * 64 + ((lj ^ swA) << 3)];
        short8 vf1 = *(const short8*)&VbS[rowA * 64 + (((4 + lj) ^ swA) << 3)];
        #pragma unroll
        for (int et = 0; et < 4; et++) {
            int e = et * 16 + l15;
            int s7 = e & 7;
            short8 pf0 = *(const short8*)&PT[e * 64 + ((lj ^ s7) << 3)];
            short8 pf1 = *(const short8*)&PT[e * 64 + (((4 + lj) ^ s7) << 3)];
            oa[et] = mfma16(vf0, pf0, oa[et]);
            oa[et] = mfma16(vf1, pf1, oa[et]);
        }
    }
    #pragma unroll
    for (int et = 0; et < 4; et++) {
        #pragma unroll
        for (int r = 0; r < 4; r++) {
            int n = w * 16 + lj * 4 + r;
            if (n < VN)
                Out[((size_t)(b * VN + n)) * VD + e0 + et * 16 + l15] = oa[et][r];
        }
    }
}

extern "C" void kernel_launch(void* const* d_in, const int* in_sizes, int n_in,
                              void* d_out, int out_size, void* d_ws, size_t ws_size,
                              hipStream_t stream) {
    const float* Vis  = (const float*)d_in[0];
    const float* Aud  = (const float*)d_in[1];
    const float* aW1  = (const float*)d_in[2];
    const float* ab1  = (const float*)d_in[3];
    const float* a_g1 = (const float*)d_in[4];
    const float* a_b1 = (const float*)d_in[5];
    const float* aW2  = (const float*)d_in[6];
    const float* ab2  = (const float*)d_in[7];
    const float* vW1  = (const float*)d_in[8];
    const float* vb1  = (const float*)d_in[9];
    const float* v_g1 = (const float*)d_in[10];
    const float* v_b1 = (const float*)d_in[11];
    const float* vW2  = (const float*)d_in[12];
    const float* vb2  = (const float*)d_in[13];
    const float* kaW  = (const float*)d_in[14];
    const float* kab  = (const float*)d_in[15];
    const float* ka_g = (const float*)d_in[16];
    const float* ka_b = (const float*)d_in[17];
    const float* kvW  = (const float*)d_in[18];
    const float* kvb  = (const float*)d_in[19];
    const float* kv_g = (const float*)d_in[20];
    const float* kv_b = (const float*)d_in[21];

    float* ws = (float*)d_ws;
    float* v       = ws;                        // 1,605,632
    float* vquery  = ws + 1605632;              // 1,605,632
    float* vkeys   = ws + 2 * 1605632;          // 1,605,632
    float* vhbuf   = ws + 3 * 1605632;          // 38,416
    float* xa      = vhbuf + 38416;             // 65,536
    float* aquery  = xa + 65536;                // 131,072
    float* akeys   = aquery + 131072;           // 131,072
    float* scoresA = akeys + 131072;            // 262,144
    float* invl    = scoresA + 262144;          // 32,768
    float* stats   = invl + 32768;              // 512
    unsigned short* Qbf = (unsigned short*)(stats + 512);  // 2,097,152 ush
    unsigned short* Kbf = Qbf + 2097152;                   // 2,097,152 ush
    unsigned short* Vbf = (unsigned short*)vkeys;          // alias: vkeys dead after F4
    // total 30.3 MB (same as validated round-3 footprint)

    float* vout = (float*)d_out;                // (16,49,2048)
    float* aout = vout + 1605632;               // (16,64,128)

    F1<<<2816, 256, 0, stream>>>(Vis, Aud, aW1, ab1, kaW, kab, v, xa, akeys);
    F2<<<7184, 256, 0, stream>>>(v, vW1, vb1, vhbuf, kvW, kvb, vkeys, xa, a_g1, a_b1,
                                 akeys, ka_g, ka_b, stats);
    F3<<<610, 256, 0, stream>>>(vhbuf, v_g1, v_b1, vkeys, kv_g, kv_b, stats, xa, aW2, ab2, aquery);
    F4<<<1312, 256, 0, stream>>>(vhbuf, stats, vW2, vb2, vquery, vkeys, Kbf, akeys, aquery, scoresA);
    F5<<<1088, 256, 0, stream>>>(vquery, Qbf, Aud, scoresA, aout, Vis, Vbf);
    k_pass1<<<dim3(16, 16), 256, 0, stream>>>(Kbf, Qbf, invl);
    k_pass2<<<dim3(32, 16), 256, 0, stream>>>(Kbf, Qbf, Vbf, invl, vout);
}